// Round 4
// baseline (138.225 us; speedup 1.0000x reference)
//
#include <hip/hip_runtime.h>
#include <hip/hip_bf16.h>
#include <stdint.h>

// Problem constants: B=8, T=2048, C=1024, H=64. Single-head causal attention.
#define Bn 8
#define Tn 2048
#define Cn 1024
#define Hn 64

typedef __attribute__((ext_vector_type(8))) short bf16x8;  // 8 bf16 (MFMA K=32 A/B frag)
typedef __attribute__((ext_vector_type(4))) short bf16x4;  // 4 bf16 (MFMA K=16 A/B frag)
typedef __attribute__((ext_vector_type(4))) float f32x4;   // MFMA C/D frag

// NOTE: __has_builtin for amdgcn builtins is false in the HOST pass (aux-target);
// only enforce on the device pass. R1 bench proved the builtin exists on gfx950
// (k_attn ran the MFMA16 path: LDS_Block_Size=0, correctness passed).
#if defined(__HIP_DEVICE_COMPILE__) && !__has_builtin(__builtin_amdgcn_mfma_f32_16x16x16bf16_1k)
#error "mfma_f32_16x16x16bf16_1k required on gfx950"
#endif
#define MFMA16(a, b, c) __builtin_amdgcn_mfma_f32_16x16x16bf16_1k(a, b, c, 0, 0, 0)
#define MFMA32(a, b, c) __builtin_amdgcn_mfma_f32_16x16x32_bf16(a, b, c, 0, 0, 0)

__device__ __forceinline__ unsigned short f2bf(float f) {
  union { float f; unsigned int u; } v; v.f = f;
  unsigned int u = v.u;
  u = u + 0x7fffu + ((u >> 16) & 1u);   // round-nearest-even
  return (unsigned short)(u >> 16);
}

// ---------------------------------------------------------------------------
// k_prep: Wt[m][h][c] = W_m[c][h] as bf16.  grid=192 (m*64+h), block=256.
// ---------------------------------------------------------------------------
__global__ __launch_bounds__(256) void k_prep(const float* __restrict__ Wq,
                                              const float* __restrict__ Wk,
                                              const float* __restrict__ Wv,
                                              unsigned short* __restrict__ Wt) {
  const int m = blockIdx.x >> 6;
  const int h = blockIdx.x & 63;
  const float* W = (m == 0) ? Wq : (m == 1) ? Wk : Wv;
  const int tid = threadIdx.x;
  unsigned short* dst = Wt + ((size_t)(m * 64 + h)) * 1024;
#pragma unroll
  for (int j = 0; j < 4; ++j) {
    int c = j * 256 + tid;
    dst[c] = f2bf(W[(size_t)c * 64 + h]);
  }
}

// ---------------------------------------------------------------------------
// k_qkv: C[16384 x 192] = x * W (Q|K|V), bf16 MFMA. 32-row x 192-col tiles,
// grid=512, block=256 (4 waves 2x2). LDS double-buffered staging with
// register-staged global loads (stage t+1 issued before compute of t);
// ONE barrier per K-step.
// ---------------------------------------------------------------------------
__global__ __launch_bounds__(256) void k_qkv(const float* __restrict__ x,
                                             const unsigned short* __restrict__ Wt,
                                             unsigned short* __restrict__ Q,
                                             unsigned short* __restrict__ K,
                                             unsigned short* __restrict__ Vt) {
  // two stages of (xs[32][72] | wsh[192][72]); os[32][200] aliases stage0.
  __shared__ __align__(16) char smem[64512];

  const int tid = threadIdx.x;
  const int lane = tid & 63;
  const int wid = tid >> 6;
  const int wm = wid >> 1, wn = wid & 1;
  const int l15 = lane & 15, g = lane >> 4;
  const int r0 = blockIdx.x * 32;
  const int srow = tid >> 3;          // 0..31
  const int scol = (tid & 7) * 8;     // 0..56

  f32x4 acc[6];
#pragma unroll
  for (int j = 0; j < 6; ++j)
#pragma unroll
    for (int r = 0; r < 4; ++r) acc[j][r] = 0.f;

  float4 xv0, xv1;
  uint4 wv[6];
  auto gload = [&](int kt) {
    const float* xp = x + (size_t)(r0 + srow) * 1024 + kt * 64 + scol;
    xv0 = *(const float4*)xp;
    xv1 = *(const float4*)(xp + 4);
#pragma unroll
    for (int j = 0; j < 6; ++j) {
      int u = j * 256 + tid;
      wv[j] = *(const uint4*)(Wt + (size_t)(u >> 3) * 1024 + kt * 64 + (u & 7) * 8);
    }
  };
  auto swrite = [&](int bb) {
    unsigned short (*xs)[72] = (unsigned short (*)[72])(smem + bb * 32256);
    unsigned short (*wsh)[72] = (unsigned short (*)[72])(smem + bb * 32256 + 32 * 72 * 2);
    ushort4 b0, b1;
    b0.x = f2bf(xv0.x); b0.y = f2bf(xv0.y); b0.z = f2bf(xv0.z); b0.w = f2bf(xv0.w);
    b1.x = f2bf(xv1.x); b1.y = f2bf(xv1.y); b1.z = f2bf(xv1.z); b1.w = f2bf(xv1.w);
    *(ushort4*)&xs[srow][scol] = b0;
    *(ushort4*)&xs[srow][scol + 4] = b1;
#pragma unroll
    for (int j = 0; j < 6; ++j) {
      int u = j * 256 + tid;
      *(uint4*)&wsh[u >> 3][(u & 7) * 8] = wv[j];
    }
  };

  gload(0);
  swrite(0);
  for (int kt = 0; kt < 16; ++kt) {
    const int cur = kt & 1;
    if (kt < 15) gload(kt + 1);          // in-flight during compute
    __syncthreads();                     // stage[cur] ready
    unsigned short (*xs)[72] = (unsigned short (*)[72])(smem + cur * 32256);
    unsigned short (*wsh)[72] = (unsigned short (*)[72])(smem + cur * 32256 + 32 * 72 * 2);
#pragma unroll
    for (int kf = 0; kf < 2; ++kf) {
      bf16x8 a = *(const bf16x8*)&xs[wm * 16 + l15][kf * 32 + g * 8];
#pragma unroll
      for (int nf = 0; nf < 6; ++nf) {
        bf16x8 bfr = *(const bf16x8*)&wsh[wn * 96 + nf * 16 + l15][kf * 32 + g * 8];
        acc[nf] = MFMA32(a, bfr, acc[nf]);
      }
    }
    if (kt < 15) swrite(cur ^ 1);        // other buffer: no conflict with readers
  }

  // epilogue: acc -> os (bf16). D layout: col = l&15, row = 4*(l>>4)+reg.
  unsigned short (*os)[200] = (unsigned short (*)[200])smem;
#pragma unroll
  for (int nf = 0; nf < 6; ++nf)
#pragma unroll
    for (int r = 0; r < 4; ++r)
      os[wm * 16 + 4 * g + r][wn * 96 + nf * 16 + l15] = f2bf(acc[nf][r]);
  __syncthreads();

  const int b = r0 >> 11;
  const int t0 = r0 & 2047;
  {
    int row = tid >> 3, ch = tid & 7;
    *(uint4*)(Q + (size_t)(r0 + row) * 64 + ch * 8) = *(const uint4*)&os[row][ch * 8];
    *(uint4*)(K + (size_t)(r0 + row) * 64 + ch * 8) = *(const uint4*)&os[row][64 + ch * 8];
  }
  {
    int h = tid >> 2, tc = (tid & 3) * 8;
    unsigned short tmp[8];
#pragma unroll
    for (int r = 0; r < 8; ++r) tmp[r] = os[tc + r][128 + h];
    *(uint4*)(Vt + ((size_t)b * 64 + h) * 2048 + t0 + tc) = *(const uint4*)tmp;
  }
}

// ---------------------------------------------------------------------------
// k_attn<SEG>: flash attention, causal, swapped QK^T; wave-task =
// (b, 16-row q-tile, SEG-key segment). K register double-buffer prefetch,
// V issued early, defer-max (skip rescale unless any partial max > m+8).
// SEG=2048 degenerates to the unsplit fallback (all direct writes).
// ---------------------------------------------------------------------------
template <int SEG>
__global__ __launch_bounds__(256, 3) void k_attn(const unsigned short* __restrict__ Q,
                                                 const unsigned short* __restrict__ K,
                                                 const unsigned short* __restrict__ Vt,
                                                 float* __restrict__ out,
                                                 float* __restrict__ po,
                                                 float* __restrict__ pml) {
  constexpr int G = SEG / 16;                  // q-tiles per seg-count group
  constexpr int NS = Tn / SEG;                 // max segments per q-tile
  constexpr int TPB = G * NS * (NS + 1) / 2;   // tasks per batch

  const int tid = threadIdx.x;
  const int lane = tid & 63;
  const int l15 = lane & 15, g = lane >> 4;
  const int wid = __builtin_amdgcn_readfirstlane(tid >> 6);
  const int task = blockIdx.x * 4 + wid;

  const int b = task / TPB;                    // compile-time divisor
  const int id = task - b * TPB;
  int gg = 0;
#pragma unroll
  for (int t = 1; t < NS; ++t)
    if (id >= G * t * (t + 1) / 2) gg = t;
  const int rem = id - G * gg * (gg + 1) / 2;
  const int ql = rem / (gg + 1);
  const int s = rem - ql * (gg + 1);
  const int qt = gg * G + ql;
  const int q0 = qt * 16;
  const int klo = SEG * s;
  const int khi = min(klo + SEG, q0 + 16);

  const unsigned short* Qb = Q + (size_t)b * Tn * Hn;
  const unsigned short* Kb = K + (size_t)b * Tn * Hn;
  const unsigned short* Vb = Vt + (size_t)b * Hn * Tn;

  // Q as B-operand: lane l15 = q row, k = 8g+j
  bf16x8 bq0 = *(const bf16x8*)(Qb + (size_t)(q0 + l15) * 64 + g * 8);
  bf16x8 bq1 = *(const bf16x8*)(Qb + (size_t)(q0 + l15) * 64 + 32 + g * 8);

  f32x4 o[4];
#pragma unroll
  for (int hf = 0; hf < 4; ++hf)
#pragma unroll
    for (int r = 0; r < 4; ++r) o[hf][r] = 0.f;
  float m = -1e30f, lsum = 0.f;
  const float sc = 0.03125f * 1.44269504088896f;  // C^-0.5 * log2(e)

  const int nt = (khi - klo + 63) >> 6;

  bf16x8 kA[8], kB[8];
  auto loadK = [&](bf16x8* kb, int k0) {
#pragma unroll
    for (int kc = 0; kc < 4; ++kc) {
      const unsigned short* kp = Kb + (size_t)(k0 + kc * 16 + l15) * 64 + g * 8;
      kb[2 * kc] = *(const bf16x8*)kp;
      kb[2 * kc + 1] = *(const bf16x8*)(kp + 32);
    }
  };
  auto step = [&](const bf16x8* kb, int k0) {
    // V frags issued first (independent -> latency hides under MFMA+softmax)
    bf16x4 vf[4][4];
#pragma unroll
    for (int hf = 0; hf < 4; ++hf) {
      const unsigned short* vrow = Vb + (size_t)(hf * 16 + l15) * Tn + k0 + 4 * g;
#pragma unroll
      for (int kc = 0; kc < 4; ++kc)
        vf[hf][kc] = *(const bf16x4*)(vrow + kc * 16);
    }
    // S^T: lane l15 = q, reg (kc, 4g+r) = key
    f32x4 sacc[4];
#pragma unroll
    for (int kc = 0; kc < 4; ++kc) {
#pragma unroll
      for (int r = 0; r < 4; ++r) sacc[kc][r] = 0.f;
      sacc[kc] = MFMA32(kb[2 * kc], bq0, sacc[kc]);
      sacc[kc] = MFMA32(kb[2 * kc + 1], bq1, sacc[kc]);
    }
    float sv[4][4];
    if (k0 + 63 > q0) {             // boundary tile: mask (wave-uniform branch)
      const int q = q0 + l15;
#pragma unroll
      for (int kc = 0; kc < 4; ++kc)
#pragma unroll
        for (int r = 0; r < 4; ++r) {
          int key = k0 + kc * 16 + 4 * g + r;
          sv[kc][r] = (key <= q) ? sacc[kc][r] * sc : -1e30f;
        }
    } else {
#pragma unroll
      for (int kc = 0; kc < 4; ++kc)
#pragma unroll
        for (int r = 0; r < 4; ++r) sv[kc][r] = sacc[kc][r] * sc;
    }
    // defer-max: partial (lane-local) max suffices for the trigger test
    float pm = sv[0][0];
#pragma unroll
    for (int kc = 0; kc < 4; ++kc)
#pragma unroll
      for (int r = 0; r < 4; ++r) pm = fmaxf(pm, sv[kc][r]);
    if (__any(pm > m + 8.f)) {      // rare after tile 0
      pm = fmaxf(pm, __shfl_xor(pm, 16));
      pm = fmaxf(pm, __shfl_xor(pm, 32));
      float mn = fmaxf(m, pm);
      float alpha = exp2f(m - mn);
      lsum *= alpha;
      float an[4];
#pragma unroll
      for (int r = 0; r < 4; ++r) an[r] = __shfl(alpha, 4 * g + r);
#pragma unroll
      for (int hf = 0; hf < 4; ++hf)
#pragma unroll
        for (int r = 0; r < 4; ++r) o[hf][r] *= an[r];
      m = mn;
    }
    float p[4][4], ts = 0.f;
#pragma unroll
    for (int kc = 0; kc < 4; ++kc)
#pragma unroll
      for (int r = 0; r < 4; ++r) { p[kc][r] = exp2f(sv[kc][r] - m); ts += p[kc][r]; }
    ts += __shfl_xor(ts, 16);
    ts += __shfl_xor(ts, 32);
    lsum += ts;
    // P already in K=16 A-operand layout: lane l15 = q, k-local = 4g+r
    bf16x4 pa[4];
#pragma unroll
    for (int kc = 0; kc < 4; ++kc) {
      pa[kc][0] = (short)f2bf(p[kc][0]); pa[kc][1] = (short)f2bf(p[kc][1]);
      pa[kc][2] = (short)f2bf(p[kc][2]); pa[kc][3] = (short)f2bf(p[kc][3]);
    }
#pragma unroll
    for (int hf = 0; hf < 4; ++hf)
#pragma unroll
      for (int kc = 0; kc < 4; ++kc)
        o[hf] = MFMA16(pa[kc], vf[hf][kc], o[hf]);
  };

  loadK(kA, klo);
  for (int t = 0; t < nt; t += 2) {
    if (t + 1 < nt) loadK(kB, klo + (t + 1) * 64);   // prefetch next tile
    step(kA, klo + t * 64);
    if (t + 1 >= nt) break;
    if (t + 2 < nt) loadK(kA, klo + (t + 2) * 64);
    step(kB, klo + (t + 1) * 64);
  }

  if (NS > 1 && qt >= G) {
    // partial: unnormalized o + (m, l)
    const int slot = (b * (128 - G) + (qt - G)) * NS + s;
    float* pob = po + (size_t)slot * 1024;
#pragma unroll
    for (int hf = 0; hf < 4; ++hf)
#pragma unroll
      for (int r = 0; r < 4; ++r)
        pob[(4 * g + r) * 64 + hf * 16 + l15] = o[hf][r];
    if (lane < 16) {
      pml[slot * 32 + l15] = m;
      pml[slot * 32 + 16 + l15] = lsum;
    }
  } else {
    const float il = 1.f / lsum;
    float iln[4];
#pragma unroll
    for (int r = 0; r < 4; ++r) iln[r] = __shfl(il, 4 * g + r);
    float* ob = out + ((size_t)b * Tn + q0) * 64;
#pragma unroll
    for (int hf = 0; hf < 4; ++hf)
#pragma unroll
      for (int r = 0; r < 4; ++r)
        ob[(size_t)(4 * g + r) * 64 + hf * 16 + l15] = o[hf][r] * iln[r];
  }
}

// ---------------------------------------------------------------------------
// k_comb<SEG>: merge partial segments per (b, qt>=G). grid=(128-G, 8), block=64.
// ---------------------------------------------------------------------------
template <int SEG>
__global__ __launch_bounds__(64) void k_comb(const float* __restrict__ po,
                                             const float* __restrict__ pml,
                                             float* __restrict__ out) {
  constexpr int G = SEG / 16, NS = Tn / SEG;
  const int qt = G + blockIdx.x;
  const int b = blockIdx.y;
  const int nseg = qt / G + 1;
  const int r = threadIdx.x >> 2;
  const int cg = threadIdx.x & 3;
  const int slot0 = (b * (128 - G) + (qt - G)) * NS;

  float mv[NS], lv[NS], M = -1e30f;
#pragma unroll
  for (int s = 0; s < NS; ++s)
    if (s < nseg) {
      mv[s] = pml[(slot0 + s) * 32 + r];
      lv[s] = pml[(slot0 + s) * 32 + 16 + r];
      M = fmaxf(M, mv[s]);
    }
  float w[NS], L = 0.f;
#pragma unroll
  for (int s = 0; s < NS; ++s)
    if (s < nseg) { w[s] = exp2f(mv[s] - M); L += w[s] * lv[s]; }

  float acc[16];
#pragma unroll
  for (int c = 0; c < 16; ++c) acc[c] = 0.f;
#pragma unroll
  for (int s = 0; s < NS; ++s)
    if (s < nseg) {
      const float* pb = po + (size_t)(slot0 + s) * 1024 + r * 64 + cg * 16;
#pragma unroll
      for (int j = 0; j < 4; ++j) {
        float4 v = *(const float4*)(pb + 4 * j);
        acc[4 * j + 0] += w[s] * v.x; acc[4 * j + 1] += w[s] * v.y;
        acc[4 * j + 2] += w[s] * v.z; acc[4 * j + 3] += w[s] * v.w;
      }
    }
  const float invL = 1.f / L;
  float* ob = out + ((size_t)(b * Tn + qt * 16 + r)) * 64 + cg * 16;
#pragma unroll
  for (int j = 0; j < 4; ++j) {
    float4 v;
    v.x = acc[4 * j + 0] * invL; v.y = acc[4 * j + 1] * invL;
    v.z = acc[4 * j + 2] * invL; v.w = acc[4 * j + 3] * invL;
    *(float4*)(ob + 4 * j) = v;
  }
}

// ---------------------------------------------------------------------------
extern "C" void kernel_launch(void* const* d_in, const int* in_sizes, int n_in,
                              void* d_out, int out_size, void* d_ws, size_t ws_size,
                              hipStream_t stream) {
  const float* x  = (const float*)d_in[0];
  const float* Wq = (const float*)d_in[1];
  const float* Wk = (const float*)d_in[2];
  const float* Wv = (const float*)d_in[3];
  float* out = (float*)d_out;

  // ws layout (bf16): Wt[3*64*1024] | Q | K | Vt  (each B*T*64), then fp32 partials
  unsigned short* Wt = (unsigned short*)d_ws;
  unsigned short* Qs = Wt + 3 * 64 * 1024;
  unsigned short* Ks = Qs + (size_t)Bn * Tn * Hn;
  unsigned short* Vt = Ks + (size_t)Bn * Tn * Hn;
  const size_t bf_bytes = (3 * 64 * 1024 + 3 * (size_t)Bn * Tn * Hn) * 2;
  float* po = (float*)((char*)d_ws + bf_bytes);

  const size_t slots256 = (size_t)8 * 112 * 8;   // 7168
  const size_t slots512 = (size_t)8 * 96 * 4;    // 3072
  const size_t need256 = bf_bytes + slots256 * (1024 + 32) * 4;
  const size_t need512 = bf_bytes + slots512 * (1024 + 32) * 4;

  hipLaunchKernelGGL(k_prep, dim3(192), dim3(256), 0, stream, Wq, Wk, Wv, Wt);
  hipLaunchKernelGGL(k_qkv, dim3(512), dim3(256), 0, stream, x, Wt, Qs, Ks, Vt);
  if (ws_size >= need256) {
    float* pml = po + slots256 * 1024;
    hipLaunchKernelGGL((k_attn<256>), dim3(1152), dim3(256), 0, stream, Qs, Ks, Vt, out, po, pml);
    hipLaunchKernelGGL((k_comb<256>), dim3(112, 8), dim3(64), 0, stream, po, pml, out);
  } else if (ws_size >= need512) {
    float* pml = po + slots512 * 1024;
    hipLaunchKernelGGL((k_attn<512>), dim3(640), dim3(256), 0, stream, Qs, Ks, Vt, out, po, pml);
    hipLaunchKernelGGL((k_comb<512>), dim3(96, 8), dim3(64), 0, stream, po, pml, out);
  } else {
    hipLaunchKernelGGL((k_attn<2048>), dim3(256), dim3(256), 0, stream, Qs, Ks, Vt, out, po, po);
  }
}

// Round 5
// 92.591 us; speedup vs baseline: 1.4929x; 1.4929x over previous
//
#include <hip/hip_runtime.h>
#include <hip/hip_bf16.h>
#include <stdint.h>

// Problem constants: B=8, T=2048, C=1024, H=64. Single-head causal attention.
#define Bn 8
#define Tn 2048
#define Cn 1024
#define Hn 64

typedef __attribute__((ext_vector_type(8))) short bf16x8;  // 8 bf16 (MFMA K=32 A/B frag)
typedef __attribute__((ext_vector_type(4))) short bf16x4;  // 4 bf16 (MFMA K=16 A/B frag)
typedef __attribute__((ext_vector_type(4))) float f32x4;   // MFMA C/D frag

// __has_builtin for amdgcn builtins is false in the HOST pass; device-only check.
#if defined(__HIP_DEVICE_COMPILE__) && !__has_builtin(__builtin_amdgcn_mfma_f32_16x16x16bf16_1k)
#error "mfma_f32_16x16x16bf16_1k required on gfx950"
#endif
#define MFMA16(a, b, c) __builtin_amdgcn_mfma_f32_16x16x16bf16_1k(a, b, c, 0, 0, 0)
#define MFMA32(a, b, c) __builtin_amdgcn_mfma_f32_16x16x32_bf16(a, b, c, 0, 0, 0)

__device__ __forceinline__ unsigned short f2bf(float f) {
  union { float f; unsigned int u; } v; v.f = f;
  unsigned int u = v.u;
  u = u + 0x7fffu + ((u >> 16) & 1u);   // round-nearest-even
  return (unsigned short)(u >> 16);
}

// ---------------------------------------------------------------------------
// k_prep: Wt[m][h][c] = W_m[c][h] as bf16.  grid=192 (m*64+h), block=256.
// ---------------------------------------------------------------------------
__global__ __launch_bounds__(256) void k_prep(const float* __restrict__ Wq,
                                              const float* __restrict__ Wk,
                                              const float* __restrict__ Wv,
                                              unsigned short* __restrict__ Wt) {
  const int m = blockIdx.x >> 6;
  const int h = blockIdx.x & 63;
  const float* W = (m == 0) ? Wq : (m == 1) ? Wk : Wv;
  const int tid = threadIdx.x;
  unsigned short* dst = Wt + ((size_t)(m * 64 + h)) * 1024;
#pragma unroll
  for (int j = 0; j < 4; ++j) {
    int c = j * 256 + tid;
    dst[c] = f2bf(W[(size_t)c * 64 + h]);
  }
}

// ---------------------------------------------------------------------------
// k_qkv: R2-proven structure. C[16384x192] = x * W (Q|K|V), bf16 MFMA.
// 32-row x 192-col tiles, grid=512, block=256 (4 waves 2x2). Single LDS
// stage, 2 barriers/iter. launch_bounds(256,2): cap 256 VGPR -> no scratch.
// ---------------------------------------------------------------------------
__global__ __launch_bounds__(256, 2) void k_qkv(const float* __restrict__ x,
                                                const unsigned short* __restrict__ Wt,
                                                unsigned short* __restrict__ Q,
                                                unsigned short* __restrict__ K,
                                                unsigned short* __restrict__ Vt) {
  // xs[32][72] | wsh[192][72]; os[32][200] aliases for the epilogue.
  __shared__ __align__(16) char smem[32256];
  unsigned short (*xs)[72] = (unsigned short (*)[72])smem;
  unsigned short (*wsh)[72] = (unsigned short (*)[72])(smem + 32 * 72 * 2);
  unsigned short (*os)[200] = (unsigned short (*)[200])smem;

  const int tid = threadIdx.x;
  const int lane = tid & 63;
  const int wid = tid >> 6;
  const int wm = wid >> 1, wn = wid & 1;
  const int l15 = lane & 15, g = lane >> 4;
  const int r0 = blockIdx.x * 32;

  f32x4 acc[6];
#pragma unroll
  for (int j = 0; j < 6; ++j)
#pragma unroll
    for (int r = 0; r < 4; ++r) acc[j][r] = 0.f;

  const int srow = tid >> 3;          // 0..31
  const int scol = (tid & 7) * 8;     // 0..56

  for (int kt = 0; kt < 16; ++kt) {
    const int k0 = kt * 64;
    // stage x (fp32 -> bf16): 32 rows x 64 k
    const float* xp = x + (size_t)(r0 + srow) * 1024 + k0 + scol;
    {
      float4 v0 = *(const float4*)xp;
      float4 v1 = *(const float4*)(xp + 4);
      ushort4 b0, b1;
      b0.x = f2bf(v0.x); b0.y = f2bf(v0.y); b0.z = f2bf(v0.z); b0.w = f2bf(v0.w);
      b1.x = f2bf(v1.x); b1.y = f2bf(v1.y); b1.z = f2bf(v1.z); b1.w = f2bf(v1.w);
      *(ushort4*)&xs[srow][scol] = b0;
      *(ushort4*)&xs[srow][scol + 4] = b1;
    }
    // stage Wt slice (192 rows x 64 k bf16)
#pragma unroll
    for (int j = 0; j < 6; ++j) {
      int u = j * 256 + tid;
      int row = u >> 3, ch = u & 7;
      uint4 w = *(const uint4*)(Wt + (size_t)row * 1024 + k0 + ch * 8);
      *(uint4*)&wsh[row][ch * 8] = w;
    }
    __syncthreads();
#pragma unroll
    for (int kf = 0; kf < 2; ++kf) {
      bf16x8 a = *(const bf16x8*)&xs[wm * 16 + l15][kf * 32 + g * 8];
#pragma unroll
      for (int nf = 0; nf < 6; ++nf) {
        bf16x8 bfr = *(const bf16x8*)&wsh[wn * 96 + nf * 16 + l15][kf * 32 + g * 8];
        acc[nf] = MFMA32(a, bfr, acc[nf]);
      }
    }
    __syncthreads();
  }

  // epilogue: acc -> os (bf16). D layout: col = l&15, row = 4*(l>>4)+reg.
#pragma unroll
  for (int nf = 0; nf < 6; ++nf)
#pragma unroll
    for (int r = 0; r < 4; ++r)
      os[wm * 16 + 4 * g + r][wn * 96 + nf * 16 + l15] = f2bf(acc[nf][r]);
  __syncthreads();

  const int b = r0 >> 11;
  const int t0 = r0 & 2047;
  {
    int row = tid >> 3, ch = tid & 7;
    *(uint4*)(Q + (size_t)(r0 + row) * 64 + ch * 8) = *(const uint4*)&os[row][ch * 8];
    *(uint4*)(K + (size_t)(r0 + row) * 64 + ch * 8) = *(const uint4*)&os[row][64 + ch * 8];
  }
  {
    int h = tid >> 2, tc = (tid & 3) * 8;
    unsigned short tmp[8];
#pragma unroll
    for (int r = 0; r < 8; ++r) tmp[r] = os[tc + r][128 + h];
    *(uint4*)(Vt + ((size_t)b * 64 + h) * 2048 + t0 + tc) = *(const uint4*)tmp;
  }
}

// ---------------------------------------------------------------------------
// k_attn<SEG>: flash attention, causal, swapped QK^T; wave-task =
// (b, 16-row q-tile, SEG-key segment). Single K reg-buffer refilled after
// its MFMAs consume it (1-tile pipeline); V issued at tile top. VGPR-budget
// via launch_bounds(256,2) so all ~24 loads/tile stay in flight (the R2/R4
// regression was the allocator serializing loads to hit a 64-VGPR tier).
// ---------------------------------------------------------------------------
template <int SEG>
__global__ __launch_bounds__(256, 2) void k_attn(const unsigned short* __restrict__ Q,
                                                 const unsigned short* __restrict__ K,
                                                 const unsigned short* __restrict__ Vt,
                                                 float* __restrict__ out,
                                                 float* __restrict__ po,
                                                 float* __restrict__ pml) {
  constexpr int G = SEG / 16;                  // q-tiles per seg-count group
  constexpr int NS = Tn / SEG;                 // max segments per q-tile
  constexpr int TPB = G * NS * (NS + 1) / 2;   // tasks per batch

  const int tid = threadIdx.x;
  const int lane = tid & 63;
  const int l15 = lane & 15, g = lane >> 4;
  const int wid = tid >> 6;
  const int task = blockIdx.x * 4 + wid;

  const int b = task / TPB;                    // compile-time divisor
  const int id = task - b * TPB;
  int gg = 0;
#pragma unroll
  for (int t = 1; t < NS; ++t)
    if (id >= G * t * (t + 1) / 2) gg = t;
  const int rem = id - G * gg * (gg + 1) / 2;
  const int ql = rem / (gg + 1);
  const int s = rem - ql * (gg + 1);
  const int qt = gg * G + ql;
  const int q0 = qt * 16;
  const int klo = SEG * s;
  const int khi = min(klo + SEG, q0 + 16);
  const int nt = (khi - klo + 63) >> 6;

  const unsigned short* Qb = Q + (size_t)b * Tn * Hn;
  const unsigned short* Kb = K + (size_t)b * Tn * Hn;
  const unsigned short* Vb = Vt + (size_t)b * Hn * Tn;

  // Q as B-operand: lane l15 = q row, k = 8g+j
  bf16x8 bq0 = *(const bf16x8*)(Qb + (size_t)(q0 + l15) * 64 + g * 8);
  bf16x8 bq1 = *(const bf16x8*)(Qb + (size_t)(q0 + l15) * 64 + 32 + g * 8);

  f32x4 o[4];
#pragma unroll
  for (int hf = 0; hf < 4; ++hf)
#pragma unroll
    for (int r = 0; r < 4; ++r) o[hf][r] = 0.f;
  float m = -1e30f, lsum = 0.f;
  const float sc = 0.03125f * 1.44269504088896f;  // C^-0.5 * log2(e)

  bf16x8 kb[8];
  auto loadK = [&](int k0) {
#pragma unroll
    for (int kc = 0; kc < 4; ++kc) {
      const unsigned short* kp = Kb + (size_t)(k0 + kc * 16 + l15) * 64 + g * 8;
      kb[2 * kc] = *(const bf16x8*)kp;
      kb[2 * kc + 1] = *(const bf16x8*)(kp + 32);
    }
  };

  loadK(klo);
  for (int t = 0; t < nt; ++t) {
    const int k0 = klo + t * 64;
    // V frags issued first: consumed only after softmax (latency covered)
    bf16x4 vf[4][4];
#pragma unroll
    for (int hf = 0; hf < 4; ++hf) {
      const unsigned short* vrow = Vb + (size_t)(hf * 16 + l15) * Tn + k0 + 4 * g;
#pragma unroll
      for (int kc = 0; kc < 4; ++kc)
        vf[hf][kc] = *(const bf16x4*)(vrow + kc * 16);
    }
    // S^T: lane l15 = q, reg (kc, 4g+r) = key   (consumes kb)
    f32x4 sacc[4];
#pragma unroll
    for (int kc = 0; kc < 4; ++kc) {
#pragma unroll
      for (int r = 0; r < 4; ++r) sacc[kc][r] = 0.f;
      sacc[kc] = MFMA32(kb[2 * kc], bq0, sacc[kc]);
      sacc[kc] = MFMA32(kb[2 * kc + 1], bq1, sacc[kc]);
    }
    // kb is dead now: refill with next tile's K (lands during softmax+PV)
    if (t + 1 < nt) loadK(k0 + 64);
    // scale + causal mask (key <= q); boundary tiles only (wave-uniform)
    float sv[4][4];
    if (k0 + 63 > q0) {
      const int q = q0 + l15;
#pragma unroll
      for (int kc = 0; kc < 4; ++kc)
#pragma unroll
        for (int r = 0; r < 4; ++r) {
          int key = k0 + kc * 16 + 4 * g + r;
          sv[kc][r] = (key <= q) ? sacc[kc][r] * sc : -1e30f;
        }
    } else {
#pragma unroll
      for (int kc = 0; kc < 4; ++kc)
#pragma unroll
        for (int r = 0; r < 4; ++r) sv[kc][r] = sacc[kc][r] * sc;
    }
    // defer-max: lane-local max suffices for the trigger test
    float pm = sv[0][0];
#pragma unroll
    for (int kc = 0; kc < 4; ++kc)
#pragma unroll
      for (int r = 0; r < 4; ++r) pm = fmaxf(pm, sv[kc][r]);
    if (__any(pm > m + 8.f)) {      // rare after tile 0
      pm = fmaxf(pm, __shfl_xor(pm, 16));
      pm = fmaxf(pm, __shfl_xor(pm, 32));
      float mn = fmaxf(m, pm);
      float alpha = exp2f(m - mn);
      lsum *= alpha;
      float an[4];
#pragma unroll
      for (int r = 0; r < 4; ++r) an[r] = __shfl(alpha, 4 * g + r);
#pragma unroll
      for (int hf = 0; hf < 4; ++hf)
#pragma unroll
        for (int r = 0; r < 4; ++r) o[hf][r] *= an[r];
      m = mn;
    }
    float ts = 0.f;
#pragma unroll
    for (int kc = 0; kc < 4; ++kc)
#pragma unroll
      for (int r = 0; r < 4; ++r) { sv[kc][r] = exp2f(sv[kc][r] - m); ts += sv[kc][r]; }
    ts += __shfl_xor(ts, 16);
    ts += __shfl_xor(ts, 32);
    lsum += ts;
    // P already in K=16 A-operand layout: lane l15 = q, k-local = 4g+r
    bf16x4 pa[4];
#pragma unroll
    for (int kc = 0; kc < 4; ++kc) {
      pa[kc][0] = (short)f2bf(sv[kc][0]); pa[kc][1] = (short)f2bf(sv[kc][1]);
      pa[kc][2] = (short)f2bf(sv[kc][2]); pa[kc][3] = (short)f2bf(sv[kc][3]);
    }
#pragma unroll
    for (int hf = 0; hf < 4; ++hf)
#pragma unroll
      for (int kc = 0; kc < 4; ++kc)
        o[hf] = MFMA16(pa[kc], vf[hf][kc], o[hf]);
  }

  if (NS > 1 && qt >= G) {
    // partial: unnormalized o + (m, l)
    const int slot = (b * (128 - G) + (qt - G)) * NS + s;
    float* pob = po + (size_t)slot * 1024;
#pragma unroll
    for (int hf = 0; hf < 4; ++hf)
#pragma unroll
      for (int r = 0; r < 4; ++r)
        pob[(4 * g + r) * 64 + hf * 16 + l15] = o[hf][r];
    if (lane < 16) {
      pml[slot * 32 + l15] = m;
      pml[slot * 32 + 16 + l15] = lsum;
    }
  } else {
    const float il = 1.f / lsum;
    float iln[4];
#pragma unroll
    for (int r = 0; r < 4; ++r) iln[r] = __shfl(il, 4 * g + r);
    float* ob = out + ((size_t)b * Tn + q0) * 64;
#pragma unroll
    for (int hf = 0; hf < 4; ++hf)
#pragma unroll
      for (int r = 0; r < 4; ++r)
        ob[(size_t)(4 * g + r) * 64 + hf * 16 + l15] = o[hf][r] * iln[r];
  }
}

// ---------------------------------------------------------------------------
// k_comb<SEG>: merge partial segments per (b, qt>=G). grid=(128-G, 8), block=64.
// ---------------------------------------------------------------------------
template <int SEG>
__global__ __launch_bounds__(64) void k_comb(const float* __restrict__ po,
                                             const float* __restrict__ pml,
                                             float* __restrict__ out) {
  constexpr int G = SEG / 16, NS = Tn / SEG;
  const int qt = G + blockIdx.x;
  const int b = blockIdx.y;
  const int nseg = qt / G + 1;
  const int r = threadIdx.x >> 2;
  const int cg = threadIdx.x & 3;
  const int slot0 = (b * (128 - G) + (qt - G)) * NS;

  float mv[NS], lv[NS], M = -1e30f;
#pragma unroll
  for (int s = 0; s < NS; ++s)
    if (s < nseg) {
      mv[s] = pml[(slot0 + s) * 32 + r];
      lv[s] = pml[(slot0 + s) * 32 + 16 + r];
      M = fmaxf(M, mv[s]);
    }
  float w[NS], L = 0.f;
#pragma unroll
  for (int s = 0; s < NS; ++s)
    if (s < nseg) { w[s] = exp2f(mv[s] - M); L += w[s] * lv[s]; }

  float acc[16];
#pragma unroll
  for (int c = 0; c < 16; ++c) acc[c] = 0.f;
#pragma unroll
  for (int s = 0; s < NS; ++s)
    if (s < nseg) {
      const float* pb = po + (size_t)(slot0 + s) * 1024 + r * 64 + cg * 16;
#pragma unroll
      for (int j = 0; j < 4; ++j) {
        float4 v = *(const float4*)(pb + 4 * j);
        acc[4 * j + 0] += w[s] * v.x; acc[4 * j + 1] += w[s] * v.y;
        acc[4 * j + 2] += w[s] * v.z; acc[4 * j + 3] += w[s] * v.w;
      }
    }
  const float invL = 1.f / L;
  float* ob = out + ((size_t)(b * Tn + qt * 16 + r)) * 64 + cg * 16;
#pragma unroll
  for (int j = 0; j < 4; ++j) {
    float4 v;
    v.x = acc[4 * j + 0] * invL; v.y = acc[4 * j + 1] * invL;
    v.z = acc[4 * j + 2] * invL; v.w = acc[4 * j + 3] * invL;
    *(float4*)(ob + 4 * j) = v;
  }
}

// ---------------------------------------------------------------------------
extern "C" void kernel_launch(void* const* d_in, const int* in_sizes, int n_in,
                              void* d_out, int out_size, void* d_ws, size_t ws_size,
                              hipStream_t stream) {
  const float* x  = (const float*)d_in[0];
  const float* Wq = (const float*)d_in[1];
  const float* Wk = (const float*)d_in[2];
  const float* Wv = (const float*)d_in[3];
  float* out = (float*)d_out;

  // ws layout (bf16): Wt[3*64*1024] | Q | K | Vt  (each B*T*64), then fp32 partials
  unsigned short* Wt = (unsigned short*)d_ws;
  unsigned short* Qs = Wt + 3 * 64 * 1024;
  unsigned short* Ks = Qs + (size_t)Bn * Tn * Hn;
  unsigned short* Vt = Ks + (size_t)Bn * Tn * Hn;
  const size_t bf_bytes = (3 * 64 * 1024 + 3 * (size_t)Bn * Tn * Hn) * 2;
  float* po = (float*)((char*)d_ws + bf_bytes);

  const size_t slots256 = (size_t)8 * 112 * 8;   // 7168
  const size_t slots512 = (size_t)8 * 96 * 4;    // 3072
  const size_t need256 = bf_bytes + slots256 * (1024 + 32) * 4;
  const size_t need512 = bf_bytes + slots512 * (1024 + 32) * 4;

  hipLaunchKernelGGL(k_prep, dim3(192), dim3(256), 0, stream, Wq, Wk, Wv, Wt);
  hipLaunchKernelGGL(k_qkv, dim3(512), dim3(256), 0, stream, x, Wt, Qs, Ks, Vt);
  if (ws_size >= need256) {
    float* pml = po + slots256 * 1024;
    hipLaunchKernelGGL((k_attn<256>), dim3(1152), dim3(256), 0, stream, Qs, Ks, Vt, out, po, pml);
    hipLaunchKernelGGL((k_comb<256>), dim3(112, 8), dim3(64), 0, stream, po, pml, out);
  } else if (ws_size >= need512) {
    float* pml = po + slots512 * 1024;
    hipLaunchKernelGGL((k_attn<512>), dim3(640), dim3(256), 0, stream, Qs, Ks, Vt, out, po, pml);
    hipLaunchKernelGGL((k_comb<512>), dim3(96, 8), dim3(64), 0, stream, po, pml, out);
  } else {
    hipLaunchKernelGGL((k_attn<2048>), dim3(256), dim3(256), 0, stream, Qs, Ks, Vt, out, po, po);
  }
}

// Round 6
// 55.259 us; speedup vs baseline: 2.5014x; 1.6756x over previous
//
#include <hip/hip_runtime.h>
#include <hip/hip_bf16.h>
#include <stdint.h>

// Problem constants: B=8, T=2048, C=1024, H=64. Single-head causal attention.
#define Bn 8
#define Tn 2048
#define Cn 1024
#define Hn 64

typedef __attribute__((ext_vector_type(8))) short bf16x8;  // 8 bf16 (MFMA K=32 A/B frag)
typedef __attribute__((ext_vector_type(4))) short bf16x4;  // 4 bf16 (MFMA K=16 A/B frag)
typedef __attribute__((ext_vector_type(4))) float f32x4;   // MFMA C/D frag

// __has_builtin for amdgcn builtins is false in the HOST pass; device-only check.
#if defined(__HIP_DEVICE_COMPILE__) && !__has_builtin(__builtin_amdgcn_mfma_f32_16x16x16bf16_1k)
#error "mfma_f32_16x16x16bf16_1k required on gfx950"
#endif
#define MFMA16(a, b, c) __builtin_amdgcn_mfma_f32_16x16x16bf16_1k(a, b, c, 0, 0, 0)
#define MFMA32(a, b, c) __builtin_amdgcn_mfma_f32_16x16x32_bf16(a, b, c, 0, 0, 0)

__device__ __forceinline__ unsigned short f2bf(float f) {
  union { float f; unsigned int u; } v; v.f = f;
  unsigned int u = v.u;
  u = u + 0x7fffu + ((u >> 16) & 1u);   // round-nearest-even
  return (unsigned short)(u >> 16);
}

// async global(16B/lane) -> LDS (wave-uniform dest base + lane*16)
__device__ __forceinline__ void gload16(const unsigned short* g, unsigned short* l) {
  __builtin_amdgcn_global_load_lds(
      (const __attribute__((address_space(1))) unsigned int*)(const void*)g,
      (__attribute__((address_space(3))) unsigned int*)(void*)l, 16, 0, 0);
}

// ---------------------------------------------------------------------------
// k_prep: Wt[m][h][c] = W_m[c][h] as bf16.  grid=192 (m*64+h), block=256.
// ---------------------------------------------------------------------------
__global__ __launch_bounds__(256) void k_prep(const float* __restrict__ Wq,
                                              const float* __restrict__ Wk,
                                              const float* __restrict__ Wv,
                                              unsigned short* __restrict__ Wt) {
  const int m = blockIdx.x >> 6;
  const int h = blockIdx.x & 63;
  const float* W = (m == 0) ? Wq : (m == 1) ? Wk : Wv;
  const int tid = threadIdx.x;
  unsigned short* dst = Wt + ((size_t)(m * 64 + h)) * 1024;
#pragma unroll
  for (int j = 0; j < 4; ++j) {
    int c = j * 256 + tid;
    dst[c] = f2bf(W[(size_t)c * 64 + h]);
  }
}

// ---------------------------------------------------------------------------
// k_qkv: R2-proven structure (25us). C[16384x192] = x * W (Q|K|V), bf16 MFMA.
// ---------------------------------------------------------------------------
__global__ __launch_bounds__(256, 2) void k_qkv(const float* __restrict__ x,
                                                const unsigned short* __restrict__ Wt,
                                                unsigned short* __restrict__ Q,
                                                unsigned short* __restrict__ K,
                                                unsigned short* __restrict__ Vt) {
  __shared__ __align__(16) char smem[32256];
  unsigned short (*xs)[72] = (unsigned short (*)[72])smem;
  unsigned short (*wsh)[72] = (unsigned short (*)[72])(smem + 32 * 72 * 2);
  unsigned short (*os)[200] = (unsigned short (*)[200])smem;

  const int tid = threadIdx.x;
  const int lane = tid & 63;
  const int wid = tid >> 6;
  const int wm = wid >> 1, wn = wid & 1;
  const int l15 = lane & 15, g = lane >> 4;
  const int r0 = blockIdx.x * 32;

  f32x4 acc[6];
#pragma unroll
  for (int j = 0; j < 6; ++j)
#pragma unroll
    for (int r = 0; r < 4; ++r) acc[j][r] = 0.f;

  const int srow = tid >> 3;
  const int scol = (tid & 7) * 8;

  for (int kt = 0; kt < 16; ++kt) {
    const int k0 = kt * 64;
    const float* xp = x + (size_t)(r0 + srow) * 1024 + k0 + scol;
    {
      float4 v0 = *(const float4*)xp;
      float4 v1 = *(const float4*)(xp + 4);
      ushort4 b0, b1;
      b0.x = f2bf(v0.x); b0.y = f2bf(v0.y); b0.z = f2bf(v0.z); b0.w = f2bf(v0.w);
      b1.x = f2bf(v1.x); b1.y = f2bf(v1.y); b1.z = f2bf(v1.z); b1.w = f2bf(v1.w);
      *(ushort4*)&xs[srow][scol] = b0;
      *(ushort4*)&xs[srow][scol + 4] = b1;
    }
#pragma unroll
    for (int j = 0; j < 6; ++j) {
      int u = j * 256 + tid;
      int row = u >> 3, ch = u & 7;
      uint4 w = *(const uint4*)(Wt + (size_t)row * 1024 + k0 + ch * 8);
      *(uint4*)&wsh[row][ch * 8] = w;
    }
    __syncthreads();
#pragma unroll
    for (int kf = 0; kf < 2; ++kf) {
      bf16x8 a = *(const bf16x8*)&xs[wm * 16 + l15][kf * 32 + g * 8];
#pragma unroll
      for (int nf = 0; nf < 6; ++nf) {
        bf16x8 bfr = *(const bf16x8*)&wsh[wn * 96 + nf * 16 + l15][kf * 32 + g * 8];
        acc[nf] = MFMA32(a, bfr, acc[nf]);
      }
    }
    __syncthreads();
  }

#pragma unroll
  for (int nf = 0; nf < 6; ++nf)
#pragma unroll
    for (int r = 0; r < 4; ++r)
      os[wm * 16 + 4 * g + r][wn * 96 + nf * 16 + l15] = f2bf(acc[nf][r]);
  __syncthreads();

  const int b = r0 >> 11;
  const int t0 = r0 & 2047;
  {
    int row = tid >> 3, ch = tid & 7;
    *(uint4*)(Q + (size_t)(r0 + row) * 64 + ch * 8) = *(const uint4*)&os[row][ch * 8];
    *(uint4*)(K + (size_t)(r0 + row) * 64 + ch * 8) = *(const uint4*)&os[row][64 + ch * 8];
  }
  {
    int h = tid >> 2, tc = (tid & 3) * 8;
    unsigned short tmp[8];
#pragma unroll
    for (int r = 0; r < 8; ++r) tmp[r] = os[tc + r][128 + h];
    *(uint4*)(Vt + ((size_t)b * 64 + h) * 2048 + t0 + tc) = *(const uint4*)tmp;
  }
}

// ---------------------------------------------------------------------------
// k_attn_coop: block-cooperative flash attention, causal, swapped QK^T.
// Block task = (b, 64-row q-tile qt, 256-key segment s); grid = 8*144 = 1152.
// 4 waves x 16 q-rows share K/V tiles staged in LDS (global_load_lds with
// pre-swizzled source; granule XOR (row&7) kills the 16-way read conflict),
// double-buffered, ONE barrier per 64-key tile. Waves 0-1 stage K, 2-3 V.
// Single-seg q-tiles (qt<4) write out directly; others write packed partials
// (slot = task_id - 4, 140/batch) merged by k_comb.
// ---------------------------------------------------------------------------
__global__ __launch_bounds__(256, 2) void k_attn_coop(const unsigned short* __restrict__ Q,
                                                      const unsigned short* __restrict__ K,
                                                      const unsigned short* __restrict__ Vt,
                                                      float* __restrict__ out,
                                                      float* __restrict__ po,
                                                      float* __restrict__ pml) {
  __shared__ __align__(16) unsigned short lds[2][8192];  // [buf][K 4096sh | V 4096sh]

  const int tid = threadIdx.x;
  const int lane = tid & 63;
  const int l15 = lane & 15, g = lane >> 4;
  const int wid = __builtin_amdgcn_readfirstlane(tid >> 6);

  // ---- task decode: bi -> (b, id); id -> (group gq, ql, s) ----
  const int bi = blockIdx.x;
  const int b = bi / 144;
  const int id = bi - b * 144;
  int gq = 0;
#pragma unroll
  for (int t = 1; t < 8; ++t)
    if (id >= 2 * t * (t + 1)) gq = t;
  const int rem = id - 2 * gq * (gq + 1);
  const int ql = rem / (gq + 1);
  const int s = rem - ql * (gq + 1);
  const int qt = 4 * gq + ql;          // 64-row q-tile 0..31
  const int qblk = qt * 64;
  const int klo = 256 * s;
  const int khi = min(klo + 256, qblk + 64);
  const int nt = (khi - klo + 63) >> 6;
  const int q0w = qblk + wid * 16;     // this wave's q rows

  const unsigned short* Qb = Q + (size_t)b * Tn * Hn;
  const unsigned short* Kb = K + (size_t)b * Tn * Hn;
  const unsigned short* Vb = Vt + (size_t)b * Hn * Tn;

  // Q as B-operand: lane l15 = q row, k = 8g+j
  bf16x8 bq0 = *(const bf16x8*)(Qb + (size_t)(q0w + l15) * 64 + g * 8);
  bf16x8 bq1 = *(const bf16x8*)(Qb + (size_t)(q0w + l15) * 64 + 32 + g * 8);

  f32x4 o[4];
#pragma unroll
  for (int hf = 0; hf < 4; ++hf)
#pragma unroll
    for (int r = 0; r < 4; ++r) o[hf][r] = 0.f;
  float m = -1e30f, lsum = 0.f;
  const float sc = 0.03125f * 1.44269504088896f;  // C^-0.5 * log2(e)

  // stage one 64-key tile: K[64key][64d] + V[64h][64key], swizzled granules.
  // granule p = wid*256 + j*64 + lane; physical granule c holds logical c^(row&7).
  auto stage = [&](int buf, int k0) {
    unsigned short* tb = &lds[buf][0];
#pragma unroll
    for (int j = 0; j < 4; ++j) {
      const int p = wid * 256 + j * 64 + lane;
      const unsigned short* src;
      if (wid < 2) {                       // K: rows = keys
        const int row = p >> 3, c = p & 7;
        src = Kb + (size_t)(k0 + row) * 64 + ((c ^ (row & 7)) * 8);
      } else {                             // V: rows = h
        const int q = p - 512;
        const int h = q >> 3, c = q & 7;
        src = Vb + (size_t)h * Tn + k0 + ((c ^ (h & 7)) * 8);
      }
      gload16(src, tb + wid * 2048 + j * 512);
    }
  };

  stage(0, klo);
  __syncthreads();

  for (int t = 0; t < nt; ++t) {
    const int cur = t & 1;
    const int k0 = klo + t * 64;
    if (t + 1 < nt) stage(cur ^ 1, klo + (t + 1) * 64);

    const unsigned short* kt = &lds[cur][0];
    const unsigned short* vt = &lds[cur][4096];

    // S^T: lane l15 = q, reg (kc, 4g+r) = key
    f32x4 sacc[4];
#pragma unroll
    for (int kc = 0; kc < 4; ++kc) {
      const int row = kc * 16 + l15;
      const int sw = row & 7;
      bf16x8 ka = *(const bf16x8*)&kt[row * 64 + ((g ^ sw) * 8)];
      bf16x8 kb2 = *(const bf16x8*)&kt[row * 64 + (((4 + g) ^ sw) * 8)];
#pragma unroll
      for (int r = 0; r < 4; ++r) sacc[kc][r] = 0.f;
      sacc[kc] = MFMA32(ka, bq0, sacc[kc]);
      sacc[kc] = MFMA32(kb2, bq1, sacc[kc]);
    }
    // scale + causal mask (key <= q); boundary tiles only (wave-uniform)
    float sv[4][4];
    if (k0 + 63 > q0w) {
      const int q = q0w + l15;
#pragma unroll
      for (int kc = 0; kc < 4; ++kc)
#pragma unroll
        for (int r = 0; r < 4; ++r) {
          int key = k0 + kc * 16 + 4 * g + r;
          sv[kc][r] = (key <= q) ? sacc[kc][r] * sc : -1e30f;
        }
    } else {
#pragma unroll
      for (int kc = 0; kc < 4; ++kc)
#pragma unroll
        for (int r = 0; r < 4; ++r) sv[kc][r] = sacc[kc][r] * sc;
    }
    // defer-max: lane-local max suffices for the trigger test
    float pm = sv[0][0];
#pragma unroll
    for (int kc = 0; kc < 4; ++kc)
#pragma unroll
      for (int r = 0; r < 4; ++r) pm = fmaxf(pm, sv[kc][r]);
    if (__any(pm > m + 8.f)) {
      pm = fmaxf(pm, __shfl_xor(pm, 16));
      pm = fmaxf(pm, __shfl_xor(pm, 32));
      float mn = fmaxf(m, pm);
      float alpha = exp2f(m - mn);
      lsum *= alpha;
      float an[4];
#pragma unroll
      for (int r = 0; r < 4; ++r) an[r] = __shfl(alpha, 4 * g + r);
#pragma unroll
      for (int hf = 0; hf < 4; ++hf)
#pragma unroll
        for (int r = 0; r < 4; ++r) o[hf][r] *= an[r];
      m = mn;
    }
    float ts = 0.f;
#pragma unroll
    for (int kc = 0; kc < 4; ++kc)
#pragma unroll
      for (int r = 0; r < 4; ++r) { sv[kc][r] = exp2f(sv[kc][r] - m); ts += sv[kc][r]; }
    ts += __shfl_xor(ts, 16);
    ts += __shfl_xor(ts, 32);
    lsum += ts;
    // P in K=16 A-operand layout: lane l15 = q, k-local = 4g+r
    bf16x4 pa[4];
#pragma unroll
    for (int kc = 0; kc < 4; ++kc) {
      pa[kc][0] = (short)f2bf(sv[kc][0]); pa[kc][1] = (short)f2bf(sv[kc][1]);
      pa[kc][2] = (short)f2bf(sv[kc][2]); pa[kc][3] = (short)f2bf(sv[kc][3]);
    }
    // V frags from LDS: B-operand lane l15 = h col, k-local = 4g+r
    bf16x4 vf[4][4];
#pragma unroll
    for (int hf = 0; hf < 4; ++hf) {
      const int h = hf * 16 + l15, hs = h & 7;
#pragma unroll
      for (int kc = 0; kc < 4; ++kc) {
        const int gran = (kc * 2 + (g >> 1)) ^ hs;
        vf[hf][kc] = *(const bf16x4*)&vt[h * 64 + gran * 8 + (g & 1) * 4];
      }
    }
#pragma unroll
    for (int hf = 0; hf < 4; ++hf)
#pragma unroll
      for (int kc = 0; kc < 4; ++kc)
        o[hf] = MFMA16(pa[kc], vf[hf][kc], o[hf]);

    __syncthreads();   // drains stage vmcnt + all waves done reading buf
  }

  if (qt >= 4) {
    // packed partial: slot = task id - 4 within batch
    const int slot = b * 140 + id - 4;
    float* pob = po + (size_t)slot * 4096;
#pragma unroll
    for (int hf = 0; hf < 4; ++hf)
#pragma unroll
      for (int r = 0; r < 4; ++r)
        pob[(16 * wid + 4 * g + r) * 64 + hf * 16 + l15] = o[hf][r];
    if (lane < 16) {
      pml[(size_t)slot * 128 + 16 * wid + l15] = m;
      pml[(size_t)slot * 128 + 64 + 16 * wid + l15] = lsum;
    }
  } else {
    const float il = 1.f / lsum;
    float iln[4];
#pragma unroll
    for (int r = 0; r < 4; ++r) iln[r] = __shfl(il, 4 * g + r);
    float* ob = out + ((size_t)b * Tn + q0w) * 64;
#pragma unroll
    for (int hf = 0; hf < 4; ++hf)
#pragma unroll
      for (int r = 0; r < 4; ++r)
        ob[(size_t)(4 * g + r) * 64 + hf * 16 + l15] = o[hf][r] * iln[r];
  }
}

// ---------------------------------------------------------------------------
// k_comb: merge 2..8 segments per (b, qt 4..31). grid=(28,8), block=256.
// Thread: row r = tid>>2 (64 rows), cg = tid&3 (16 h-cols each).
// ---------------------------------------------------------------------------
__global__ __launch_bounds__(256) void k_comb(const float* __restrict__ po,
                                              const float* __restrict__ pml,
                                              float* __restrict__ out) {
  const int qt = 4 + blockIdx.x;
  const int b = blockIdx.y;
  const int gq = qt >> 2, ql = qt & 3;
  const int nseg = gq + 1;
  const int base = b * 140 + 2 * gq * (gq + 1) + ql * (gq + 1) - 4;
  const int r = threadIdx.x >> 2;
  const int cg = threadIdx.x & 3;

  float mv[8], lv[8], M = -1e30f;
#pragma unroll
  for (int s = 0; s < 8; ++s)
    if (s < nseg) {
      mv[s] = pml[(size_t)(base + s) * 128 + r];
      lv[s] = pml[(size_t)(base + s) * 128 + 64 + r];
      M = fmaxf(M, mv[s]);
    }
  float w[8], L = 0.f;
#pragma unroll
  for (int s = 0; s < 8; ++s)
    if (s < nseg) { w[s] = exp2f(mv[s] - M); L += w[s] * lv[s]; }

  float acc[16];
#pragma unroll
  for (int c = 0; c < 16; ++c) acc[c] = 0.f;
#pragma unroll
  for (int s = 0; s < 8; ++s)
    if (s < nseg) {
      const float* pb = po + (size_t)(base + s) * 4096 + r * 64 + cg * 16;
#pragma unroll
      for (int j = 0; j < 4; ++j) {
        float4 v = *(const float4*)(pb + 4 * j);
        acc[4 * j + 0] += w[s] * v.x; acc[4 * j + 1] += w[s] * v.y;
        acc[4 * j + 2] += w[s] * v.z; acc[4 * j + 3] += w[s] * v.w;
      }
    }
  const float invL = 1.f / L;
  float* ob = out + ((size_t)b * Tn + qt * 64 + r) * 64 + cg * 16;
#pragma unroll
  for (int j = 0; j < 4; ++j) {
    float4 v;
    v.x = acc[4 * j + 0] * invL; v.y = acc[4 * j + 1] * invL;
    v.z = acc[4 * j + 2] * invL; v.w = acc[4 * j + 3] * invL;
    *(float4*)(ob + 4 * j) = v;
  }
}

// ---------------------------------------------------------------------------
// k_attn_wave: per-wave fallback (full key range), for tiny workspace only.
// ---------------------------------------------------------------------------
__global__ __launch_bounds__(256, 2) void k_attn_wave(const unsigned short* __restrict__ Q,
                                                      const unsigned short* __restrict__ K,
                                                      const unsigned short* __restrict__ Vt,
                                                      float* __restrict__ out) {
  const int tid = threadIdx.x;
  const int lane = tid & 63;
  const int l15 = lane & 15, g = lane >> 4;
  const int wid = tid >> 6;
  const int task = blockIdx.x * 4 + wid;
  const int b = task >> 7, qt = task & 127;
  const int q0 = qt * 16;
  const int nt = (q0 + 16 + 63) >> 6;

  const unsigned short* Qb = Q + (size_t)b * Tn * Hn;
  const unsigned short* Kb = K + (size_t)b * Tn * Hn;
  const unsigned short* Vb = Vt + (size_t)b * Hn * Tn;

  bf16x8 bq0 = *(const bf16x8*)(Qb + (size_t)(q0 + l15) * 64 + g * 8);
  bf16x8 bq1 = *(const bf16x8*)(Qb + (size_t)(q0 + l15) * 64 + 32 + g * 8);

  f32x4 o[4];
#pragma unroll
  for (int hf = 0; hf < 4; ++hf)
#pragma unroll
    for (int r = 0; r < 4; ++r) o[hf][r] = 0.f;
  float m = -1e30f, lsum = 0.f;
  const float sc = 0.03125f * 1.44269504088896f;

  for (int t = 0; t < nt; ++t) {
    const int k0 = t * 64;
    bf16x4 vf[4][4];
#pragma unroll
    for (int hf = 0; hf < 4; ++hf) {
      const unsigned short* vrow = Vb + (size_t)(hf * 16 + l15) * Tn + k0 + 4 * g;
#pragma unroll
      for (int kc = 0; kc < 4; ++kc) vf[hf][kc] = *(const bf16x4*)(vrow + kc * 16);
    }
    f32x4 sacc[4];
#pragma unroll
    for (int kc = 0; kc < 4; ++kc) {
      const unsigned short* kp = Kb + (size_t)(k0 + kc * 16 + l15) * 64 + g * 8;
      bf16x8 ka = *(const bf16x8*)kp;
      bf16x8 kb2 = *(const bf16x8*)(kp + 32);
#pragma unroll
      for (int r = 0; r < 4; ++r) sacc[kc][r] = 0.f;
      sacc[kc] = MFMA32(ka, bq0, sacc[kc]);
      sacc[kc] = MFMA32(kb2, bq1, sacc[kc]);
    }
    float sv[4][4];
    if (k0 + 63 > q0) {
      const int q = q0 + l15;
#pragma unroll
      for (int kc = 0; kc < 4; ++kc)
#pragma unroll
        for (int r = 0; r < 4; ++r) {
          int key = k0 + kc * 16 + 4 * g + r;
          sv[kc][r] = (key <= q) ? sacc[kc][r] * sc : -1e30f;
        }
    } else {
#pragma unroll
      for (int kc = 0; kc < 4; ++kc)
#pragma unroll
        for (int r = 0; r < 4; ++r) sv[kc][r] = sacc[kc][r] * sc;
    }
    float pm = sv[0][0];
#pragma unroll
    for (int kc = 0; kc < 4; ++kc)
#pragma unroll
      for (int r = 0; r < 4; ++r) pm = fmaxf(pm, sv[kc][r]);
    if (__any(pm > m + 8.f)) {
      pm = fmaxf(pm, __shfl_xor(pm, 16));
      pm = fmaxf(pm, __shfl_xor(pm, 32));
      float mn = fmaxf(m, pm);
      float alpha = exp2f(m - mn);
      lsum *= alpha;
      float an[4];
#pragma unroll
      for (int r = 0; r < 4; ++r) an[r] = __shfl(alpha, 4 * g + r);
#pragma unroll
      for (int hf = 0; hf < 4; ++hf)
#pragma unroll
        for (int r = 0; r < 4; ++r) o[hf][r] *= an[r];
      m = mn;
    }
    float ts = 0.f;
#pragma unroll
    for (int kc = 0; kc < 4; ++kc)
#pragma unroll
      for (int r = 0; r < 4; ++r) { sv[kc][r] = exp2f(sv[kc][r] - m); ts += sv[kc][r]; }
    ts += __shfl_xor(ts, 16);
    ts += __shfl_xor(ts, 32);
    lsum += ts;
    bf16x4 pa[4];
#pragma unroll
    for (int kc = 0; kc < 4; ++kc) {
      pa[kc][0] = (short)f2bf(sv[kc][0]); pa[kc][1] = (short)f2bf(sv[kc][1]);
      pa[kc][2] = (short)f2bf(sv[kc][2]); pa[kc][3] = (short)f2bf(sv[kc][3]);
    }
#pragma unroll
    for (int hf = 0; hf < 4; ++hf)
#pragma unroll
      for (int kc = 0; kc < 4; ++kc)
        o[hf] = MFMA16(pa[kc], vf[hf][kc], o[hf]);
  }
  const float il = 1.f / lsum;
  float iln[4];
#pragma unroll
  for (int r = 0; r < 4; ++r) iln[r] = __shfl(il, 4 * g + r);
  float* ob = out + ((size_t)b * Tn + q0) * 64;
#pragma unroll
  for (int hf = 0; hf < 4; ++hf)
#pragma unroll
    for (int r = 0; r < 4; ++r)
      ob[(size_t)(4 * g + r) * 64 + hf * 16 + l15] = o[hf][r] * iln[r];
}

// ---------------------------------------------------------------------------
extern "C" void kernel_launch(void* const* d_in, const int* in_sizes, int n_in,
                              void* d_out, int out_size, void* d_ws, size_t ws_size,
                              hipStream_t stream) {
  const float* x  = (const float*)d_in[0];
  const float* Wq = (const float*)d_in[1];
  const float* Wk = (const float*)d_in[2];
  const float* Wv = (const float*)d_in[3];
  float* out = (float*)d_out;

  // ws layout (bf16): Wt[3*64*1024] | Q | K | Vt  (each B*T*64), then fp32 partials
  unsigned short* Wt = (unsigned short*)d_ws;
  unsigned short* Qs = Wt + 3 * 64 * 1024;
  unsigned short* Ks = Qs + (size_t)Bn * Tn * Hn;
  unsigned short* Vt = Ks + (size_t)Bn * Tn * Hn;
  const size_t bf_bytes = (3 * 64 * 1024 + 3 * (size_t)Bn * Tn * Hn) * 2;
  float* po = (float*)((char*)d_ws + bf_bytes);

  const size_t nslots = (size_t)Bn * 140;   // packed partial slots
  float* pml = po + nslots * 4096;
  const size_t need = bf_bytes + nslots * (4096 + 128) * sizeof(float);  // ~25 MB

  hipLaunchKernelGGL(k_prep, dim3(192), dim3(256), 0, stream, Wq, Wk, Wv, Wt);
  hipLaunchKernelGGL(k_qkv, dim3(512), dim3(256), 0, stream, x, Wt, Qs, Ks, Vt);
  if (ws_size >= need) {
    hipLaunchKernelGGL(k_attn_coop, dim3(1152), dim3(256), 0, stream, Qs, Ks, Vt, out, po, pml);
    hipLaunchKernelGGL(k_comb, dim3(28, 8), dim3(256), 0, stream, po, pml, out);
  } else {
    hipLaunchKernelGGL(k_attn_wave, dim3(256), dim3(256), 0, stream, Qs, Ks, Vt, out);
  }
}